// Round 7
// baseline (241.917 us; speedup 1.0000x reference)
//
#include <hip/hip_runtime.h>
#include <hip/hip_bf16.h>

// FastBinaryLinear: y[t,o] = scale[o] * sum_i x[t,i]*sign(w[o,i])
// R7: i8 path, kk-sliced 4-window schedule with one-window register
// pipelining: window W reads frags for W+1 (alternate reg set) while MFMA
// runs on the set read at W-1 -> LDS pipe overlaps MFMA pipe.
// LDS byte geometry identical to verified r5/r6 kernels.

typedef int i32x4 __attribute__((ext_vector_type(4)));
typedef const __attribute__((address_space(1))) void* gptr_t;
typedef __attribute__((address_space(3))) void* lptr_t;

#define LDS_BUF 65536

template<bool V> struct BoolC { static constexpr bool value = V; };

// ---- fused pre-pass: blocks [0,M) quantize x rows; [M, M+N) sign w rows ----
__global__ __launch_bounds__(256) void prep_kernel(
    const float4* __restrict__ x, const float4* __restrict__ w,
    unsigned* __restrict__ xq, unsigned* __restrict__ wq,
    float* __restrict__ alpha, int M, int N, int K) {
  const int bid = blockIdx.x;
  const int t = threadIdx.x;
  const int n4 = K >> 2;

  if (bid < M) {
    const int row = bid;
    const float4* xr = x + (size_t)row * n4;
    unsigned* qr = xq + (size_t)row * n4;

    float m = 0.f;
    for (int i = t; i < n4; i += 256) {
      float4 v = xr[i];
      m = fmaxf(m, fmaxf(fmaxf(fabsf(v.x), fabsf(v.y)), fmaxf(fabsf(v.z), fabsf(v.w))));
    }
    for (int o = 32; o > 0; o >>= 1) m = fmaxf(m, __shfl_xor(m, o));
    __shared__ float wm[4];
    if ((t & 63) == 0) wm[t >> 6] = m;
    __syncthreads();
    m = fmaxf(fmaxf(wm[0], wm[1]), fmaxf(wm[2], wm[3]));

    const float inv = m > 0.f ? 127.f / m : 0.f;
    if (t == 0) alpha[row] = m > 0.f ? m / 127.f : 0.f;

    for (int i = t; i < n4; i += 256) {
      float4 v = xr[i];  // L1-resident re-read (row = 16KB)
      int q0 = (int)rintf(v.x * inv), q1 = (int)rintf(v.y * inv);
      int q2 = (int)rintf(v.z * inv), q3 = (int)rintf(v.w * inv);
      qr[i] = (unsigned)(q0 & 255) | ((unsigned)(q1 & 255) << 8) |
              ((unsigned)(q2 & 255) << 16) | ((unsigned)(q3 & 255) << 24);
    }
  } else {
    const int row = bid - M;
    const float4* wr = w + (size_t)row * n4;
    unsigned* qr = wq + (size_t)row * n4;
    for (int i = t; i < n4; i += 256) {
      float4 f = wr[i];
      int s0 = (f.x > 0.f) - (f.x < 0.f);
      int s1 = (f.y > 0.f) - (f.y < 0.f);
      int s2 = (f.z > 0.f) - (f.z < 0.f);
      int s3 = (f.w > 0.f) - (f.w < 0.f);
      qr[i] = (unsigned)(s0 & 255) | ((unsigned)(s1 & 255) << 8) |
              ((unsigned)(s2 & 255) << 16) | ((unsigned)(s3 & 255) << 24);
    }
  }
}

// ---- 256x256 pipelined i8 GEMM: C = A[M][K]i8 * B[N][K]^T i8, i32 exact ----
__global__ __launch_bounds__(512, 2) void gemm256_i8_kernel(
    const signed char* __restrict__ A,   // [M][K] i8 (quantized x)
    const signed char* __restrict__ B,   // [N][K] i8 (sign w)
    const float* __restrict__ scale,     // [N]
    const float* __restrict__ alpha,     // [M]
    float* __restrict__ C,               // [M][N] f32
    int M, int N, int K) {
  __shared__ __align__(16) char lds[131072];

  const int t = threadIdx.x;
  const int lane = t & 63;
  const int wv = t >> 6;
  const int wm = wv >> 2;   // 0..1
  const int wn = wv & 3;    // 0..3

  const int nbn = N >> 8;
  const int bn = blockIdx.x % nbn;
  const int bm = blockIdx.x / nbn;
  const int m0 = bm << 8, n0 = bn << 8;

  // staging coords: 8KB issue = 64 rows x 128 bytes; inverse granule swizzle
  const int rlo = ((t >> 7) << 4) | ((t >> 2) & 15);
  const int gsw = (t & 3) ^ ((t >> 3) & 3);
  const int c0b = (((t >> 6) & 1) << 6) | (gsw << 4);   // byte col
  const signed char* gA = A + (size_t)(m0 + rlo) * K + c0b;
  const signed char* gB = B + (size_t)(n0 + rlo) * K + c0b;
  const int stBase = wv << 10;  // wave-uniform LDS base; HW adds lane*16

  // ds_read lane bases (swizzled granule), all in bytes
  const int rho = lane & 15;
  const int gpr = (lane >> 4) ^ ((lane >> 1) & 3);
  const int dsA = (wm << 14) + (rho << 6) + (gpr << 4);
  const int dsB = 32768 + ((wn >> 1) << 14) + ((wn & 1) << 13) + (rho << 6) + (gpr << 4);

#define STAGE(MAT, HALF, G64, KT, BUF)                                                    \
  __builtin_amdgcn_global_load_lds(                                                       \
      (gptr_t)(((MAT) ? gB : gA) + (size_t)((HALF)*128 + (G64)*64) * K + (size_t)(KT)*128), \
      (lptr_t)(lds + (BUF)*LDS_BUF + (MAT)*32768 + (HALF)*16384 + (G64)*8192 + stBase),   \
      16, 0, 0)
#define STAGE_FULL(MAT, KT, BUF)                                      \
  STAGE(MAT, 0, 0, KT, BUF); STAGE(MAT, 0, 1, KT, BUF);               \
  STAGE(MAT, 1, 0, KT, BUF); STAGE(MAT, 1, 1, KT, BUF)

#define RD_A(MF, KK, BUF) (*(const i32x4*)(lds + (BUF)*LDS_BUF + dsA + ((MF)*2 + (KK))*1024))
#define RD_B(NF, KK, BUF) (*(const i32x4*)(lds + (BUF)*LDS_BUF + dsB + ((NF)*2 + (KK))*1024))
#define BAR() asm volatile("s_barrier" ::: "memory")
#define VMC(N) asm volatile("s_waitcnt vmcnt(" #N ")" ::: "memory")
#define LGKM0() asm volatile("s_waitcnt lgkmcnt(0)" ::: "memory")
#define LOAD_A8(DST, KK, BUF)                                         \
  _Pragma("unroll")                                                   \
  for (int mf = 0; mf < 8; mf++) DST[mf] = RD_A(mf, KK, BUF)
#define LOAD_B4(DST, KK, BUF)                                         \
  _Pragma("unroll")                                                   \
  for (int nf = 0; nf < 4; nf++) DST[nf] = RD_B(nf, KK, BUF)
#define MFMA32(AS, BS)                                                \
  __builtin_amdgcn_s_setprio(1);                                      \
  _Pragma("unroll")                                                   \
  for (int mf = 0; mf < 8; mf++)                                      \
    _Pragma("unroll")                                                 \
    for (int nf = 0; nf < 4; nf++)                                    \
      acc[mf][nf] = __builtin_amdgcn_mfma_i32_16x16x64_i8(            \
          AS[mf], BS[nf], acc[mf][nf], 0, 0, 0);                      \
  __builtin_amdgcn_s_setprio(0)

  i32x4 acc[8][4];
#pragma unroll
  for (int i = 0; i < 8; i++)
#pragma unroll
    for (int j = 0; j < 4; j++) acc[i][j] = (i32x4)(0);

  i32x4 aX[8], aY[8], bX[4], bY[4];

  // ---- prologue: stage T0->b0, T1->b1; wait T0; read (b0,kk0) ----
  STAGE_FULL(0, 0, 0); STAGE_FULL(1, 0, 0);
  STAGE_FULL(0, 1, 1); STAGE_FULL(1, 1, 1);
  VMC(8);
  BAR();
  LOAD_A8(aX, 0, 0); LOAD_B4(bX, 0, 0);

  // Steady state (T2=2i+2 -> b0, T3=2i+3 -> b1), 4 windows per iter:
  //  W0: read (b0,kk1)->Y;            MFMA X   [b0 fully read after W0]
  //  W1: stage b0<-T2 (8); VMC(8) [T1 done]; read (b1,kk0)->X; MFMA Y
  //  W2: read (b1,kk1)->Y;            MFMA X   [b1 fully read after W2]
  //  W3: stage b1<-T3 (8); VMC(8) [T2 done]; read (b0',kk0)->X; MFMA Y
  // Every window ends: lgkmcnt(0) (reads drained -> WAR-safe) + s_barrier.
  auto run_iter = [&](int i, auto fullc) {
    constexpr bool FULL = decltype(fullc)::value;
    const int kt2 = 2 * i + 2, kt3 = 2 * i + 3;

    // ===== W0 =====
    LOAD_A8(aY, 1, 0); LOAD_B4(bY, 1, 0);
    MFMA32(aX, bX);
    LGKM0(); BAR();

    // ===== W1 =====
    if constexpr (FULL) { STAGE_FULL(0, kt2, 0); STAGE_FULL(1, kt2, 0); VMC(8); }
    else                { VMC(0); }
    LOAD_A8(aX, 0, 1); LOAD_B4(bX, 0, 1);
    MFMA32(aY, bY);
    LGKM0(); BAR();

    // ===== W2 =====
    LOAD_A8(aY, 1, 1); LOAD_B4(bY, 1, 1);
    MFMA32(aX, bX);
    LGKM0(); BAR();

    // ===== W3 =====
    if constexpr (FULL) {
      STAGE_FULL(0, kt3, 1); STAGE_FULL(1, kt3, 1); VMC(8);
      LOAD_A8(aX, 0, 0); LOAD_B4(bX, 0, 0);
    }
    MFMA32(aY, bY);
    LGKM0(); BAR();
  };

  const int half_nt = K >> 8;   // 256 i8 elems per iter (2 tiles x 128B)
  for (int i = 0; i < half_nt - 1; ++i) run_iter(i, BoolC<true>{});
  run_iter(half_nt - 1, BoolC<false>{});

  // ---- epilogue: C/D col=lane&15, row=(lane>>4)*4+j; y = acc*alpha*scale ----
  const int cc = lane & 15;
  const int cr4 = (lane >> 4) << 2;
#pragma unroll
  for (int nf = 0; nf < 4; nf++) {
    const int col = n0 + wn * 64 + nf * 16 + cc;
    const float s = scale[col];
#pragma unroll
    for (int mf = 0; mf < 8; mf++) {
      const int row = m0 + wm * 128 + mf * 16 + cr4;
#pragma unroll
      for (int j = 0; j < 4; j++)
        C[(size_t)(row + j) * N + col] = (float)acc[mf][nf][j] * (s * alpha[row + j]);
    }
  }
#undef STAGE
#undef STAGE_FULL
#undef RD_A
#undef RD_B
#undef BAR
#undef VMC
#undef LGKM0
#undef LOAD_A8
#undef LOAD_B4
#undef MFMA32
}

// ---- fallback: f32 tiled GEMM (odd shapes / tiny ws) ----
__global__ __launch_bounds__(256) void fallback_gemm_kernel(
    const float* __restrict__ x, const float* __restrict__ w,
    const float* __restrict__ scale, float* __restrict__ out,
    int M, int N, int K) {
  __shared__ float xs[16][17];
  __shared__ float ws_[16][17];
  int nb = N / 16;
  int bx = blockIdx.x % nb;
  int by = blockIdx.x / nb;
  int tx = threadIdx.x % 16;
  int ty = threadIdx.x / 16;
  float acc = 0.f;
  for (int k0 = 0; k0 < K; k0 += 16) {
    xs[ty][tx] = x[(size_t)(by * 16 + ty) * K + k0 + tx];
    float wv = w[(size_t)(bx * 16 + ty) * K + k0 + tx];
    ws_[ty][tx] = (float)((wv > 0.f) - (wv < 0.f));
    __syncthreads();
#pragma unroll
    for (int kk = 0; kk < 16; kk++) acc += xs[ty][kk] * ws_[tx][kk];
    __syncthreads();
  }
  int row = by * 16 + ty, col = bx * 16 + tx;
  out[(size_t)row * N + col] = acc * scale[col];
}

extern "C" void kernel_launch(void* const* d_in, const int* in_sizes, int n_in,
                              void* d_out, int out_size, void* d_ws, size_t ws_size,
                              hipStream_t stream) {
  const float* x = (const float*)d_in[0];
  const float* w = (const float*)d_in[1];
  const float* scale = (const float*)d_in[2];
  float* out = (float*)d_out;

  const int N = in_sizes[2];
  const int K = in_sizes[1] / N;
  const int M = in_sizes[0] / K;

  const size_t xq_bytes = (size_t)M * K;
  const size_t wq_bytes = (size_t)N * K;
  const size_t al_bytes = (size_t)M * 4;
  const bool shapes_ok = (M % 256 == 0) && (N % 256 == 0) && (K % 1024 == 0);

  if (shapes_ok && ws_size >= xq_bytes + wq_bytes + al_bytes) {
    signed char* xq = (signed char*)d_ws;
    signed char* wq = (signed char*)((char*)d_ws + xq_bytes);
    float* alpha = (float*)((char*)d_ws + xq_bytes + wq_bytes);

    prep_kernel<<<M + N, 256, 0, stream>>>((const float4*)x, (const float4*)w,
                                           (unsigned*)xq, (unsigned*)wq, alpha, M, N, K);

    int grid = (M / 256) * (N / 256);
    gemm256_i8_kernel<<<grid, 512, 0, stream>>>(xq, wq, scale, alpha, out, M, N, K);
  } else {
    int grid = (M / 16) * (N / 16);
    fallback_gemm_kernel<<<grid, 256, 0, stream>>>(x, w, scale, out, M, N, K);
  }
}